// Round 11
// baseline (92.974 us; speedup 1.0000x reference)
//
#include <hip/hip_runtime.h>
#include <hip/hip_bf16.h>

#define T_SEQ 4096
#define DMODEL 1024
#define NH 16
#define DH 64
#define N_QKV 3072
#define N_QK 2048

typedef __attribute__((ext_vector_type(8))) short bf16x8;
typedef __attribute__((ext_vector_type(4))) float f32x4;

__device__ inline void gload_lds16(const __hip_bfloat16* g, __hip_bfloat16* l) {
  __builtin_amdgcn_global_load_lds(
      (const __attribute__((address_space(1))) void*)g,
      (__attribute__((address_space(3))) void*)l, 16, 0, 0);
}

// ---------------- fused prep: cast x + transpose both weights ----------------
__global__ void prep_kernel(const float* __restrict__ x,
                            const float* __restrict__ w_qkv,
                            const float* __restrict__ w_out,
                            __hip_bfloat16* __restrict__ x_bf,
                            __hip_bfloat16* __restrict__ wqkvT,
                            __hip_bfloat16* __restrict__ woutT) {
  __shared__ float tile[32][33];
  const int b = blockIdx.x;
  if (b < 4096) {
    int i = (b * 256 + threadIdx.x) * 4;
    float4 v = *(const float4*)(x + i);
    ushort4 o;
    o.x = __bfloat16_as_ushort(__float2bfloat16(v.x));
    o.y = __bfloat16_as_ushort(__float2bfloat16(v.y));
    o.z = __bfloat16_as_ushort(__float2bfloat16(v.z));
    o.w = __bfloat16_as_ushort(__float2bfloat16(v.w));
    *(ushort4*)((unsigned short*)x_bf + i) = o;
    return;
  }
  const float* in;
  __hip_bfloat16* out;
  int NN, KK, bn, bk;
  if (b < 7168) {
    int idx = b - 4096;
    in = w_qkv; out = wqkvT; NN = N_QKV; KK = DMODEL;
    bn = (idx % 96) * 32; bk = (idx / 96) * 32;
  } else {
    int idx = b - 7168;
    in = w_out; out = woutT; NN = DMODEL; KK = DMODEL;
    bn = (idx % 32) * 32; bk = (idx / 32) * 32;
  }
  int tx = threadIdx.x & 31, ty = threadIdx.x >> 5;
#pragma unroll
  for (int r = 0; r < 32; r += 8)
    tile[ty + r][tx] = in[(size_t)(bk + ty + r) * NN + bn + tx];
  __syncthreads();
#pragma unroll
  for (int r = 0; r < 32; r += 8)
    out[(size_t)(bn + ty + r) * KK + bk + tx] = __float2bfloat16(tile[tx][ty + r]);
}

// ======== 256x256 8-phase QKV GEMM, half-tile ring (4 slots/operand) ========
// A: 4096x1024. Bt: 3072x1024. Writes: cols<2048 -> qk (Q scaled); else vt^T.
// Interleaved wave tiling: row = m*32 + wr*16, col = n*64 + wc*16 -> each
// phase (qm,qn) touches exactly one A-half and one B-half for all waves.
// Per K-tile t: 4 phases; stage [A(t+1)h0 @p1, B(t+1)h0 @p2, A(t+1)h1 @p3,
// B(t+1)h1 @p4]; gates vmcnt(4) at p1,p2,p4 (ledger-verified race-free).
__global__ __launch_bounds__(512, 2) void gemm8_qkv(
    const __hip_bfloat16* __restrict__ A, const __hip_bfloat16* __restrict__ Bt,
    __hip_bfloat16* __restrict__ qk, __hip_bfloat16* __restrict__ vt) {
  const int K = DMODEL;  // 16 K-tiles of 64
  __shared__ alignas(16) __hip_bfloat16 Ab[4][128 * 64];  // 64 KB ring
  __shared__ alignas(16) __hip_bfloat16 Bb[4][128 * 64];  // 64 KB ring

  const int tid = threadIdx.x;
  const int lane = tid & 63;
  const int w = tid >> 6;             // 0..7
  const int wr = w >> 2, wc = w & 3;  // 2 x 4 wave grid (interleaved tiling)
  const int frow = lane & 15, fgrp = lane >> 4;

  const int bid = blockIdx.x;                    // 192 blocks
  const int sbid = (bid & 7) * 24 + (bid >> 3);  // bijective XCD swizzle
  const int mb = sbid / 12, nb = sbid % 12;
  const int brow = mb << 8, bcol = nb << 8;

  // staging: 512 threads cover 64 rows x 8 slots of 16B per round; 2 rounds/half
  const int srow = tid >> 3;                       // 0..63
  const int sslot = (tid & 7) ^ (srow & 7);        // pre-swizzled source slot
  const __hip_bfloat16* aSrcA = A + (size_t)(brow + srow) * K + sslot * 8;
  const __hip_bfloat16* aSrcB = Bt + (size_t)(bcol + srow) * K + sslot * 8;
  const int dstOff = srow * 64 + (tid & 7) * 8;    // linear LDS dest

#define STG_A(t, h)                                                              \
  do {                                                                           \
    int _sl = (2 * (t) + (h)) & 3;                                               \
    gload_lds16(aSrcA + (size_t)((h)*128) * K + (t)*64, &Ab[_sl][dstOff]);       \
    gload_lds16(aSrcA + (size_t)((h)*128 + 64) * K + (t)*64,                     \
                &Ab[_sl][4096 + dstOff]);                                        \
  } while (0)
#define STG_B(t, h)                                                              \
  do {                                                                           \
    int _sl = (2 * (t) + (h)) & 3;                                               \
    gload_lds16(aSrcB + (size_t)((h)*128) * K + (t)*64, &Bb[_sl][dstOff]);       \
    gload_lds16(aSrcB + (size_t)((h)*128 + 64) * K + (t)*64,                     \
                &Bb[_sl][4096 + dstOff]);                                        \
  } while (0)

  f32x4 acc[8][4] = {};
  bf16x8 afr[4][2], bfr[2][2];
  const int rsw = frow & 7;  // read swizzle key (row&7 == frow&7 here)

#define READ_A(qm, t)                                                            \
  do {                                                                           \
    const __hip_bfloat16* _as = &Ab[(2 * (t) + (qm)) & 3][0];                    \
    _Pragma("unroll") for (int m = 0; m < 4; m++) {                              \
      int loc = m * 32 + wr * 16 + frow;                                         \
      _Pragma("unroll") for (int kh = 0; kh < 2; kh++)                           \
          afr[m][kh] =                                                           \
          *(const bf16x8*)(_as + loc * 64 + (((kh * 4 + fgrp) ^ rsw) << 3));     \
    }                                                                            \
  } while (0)
#define READ_B(qn, t)                                                            \
  do {                                                                           \
    const __hip_bfloat16* _bs = &Bb[(2 * (t) + (qn)) & 3][0];                    \
    _Pragma("unroll") for (int n = 0; n < 2; n++) {                              \
      int loc = n * 64 + wc * 16 + frow;                                         \
      _Pragma("unroll") for (int kh = 0; kh < 2; kh++)                           \
          bfr[n][kh] =                                                           \
          *(const bf16x8*)(_bs + loc * 64 + (((kh * 4 + fgrp) ^ rsw) << 3));     \
    }                                                                            \
  } while (0)
#define MMA(qm, qn)                                                              \
  do {                                                                           \
    __builtin_amdgcn_s_setprio(1);                                               \
    _Pragma("unroll") for (int m = 0; m < 4; m++)                                \
        _Pragma("unroll") for (int n = 0; n < 2; n++)                            \
            _Pragma("unroll") for (int kh = 0; kh < 2; kh++)                     \
                acc[(qm)*4 + m][(qn)*2 + n] =                                    \
        __builtin_amdgcn_mfma_f32_16x16x32_bf16(                                 \
            afr[m][kh], bfr[n][kh], acc[(qm)*4 + m][(qn)*2 + n], 0, 0, 0);       \
    __builtin_amdgcn_s_setprio(0);                                               \
  } while (0)

  // prologue: tile 0's four half-tiles; gate h0 pair
  STG_A(0, 0);
  STG_B(0, 0);
  STG_A(0, 1);
  STG_B(0, 1);
  asm volatile("s_waitcnt vmcnt(4)" ::: "memory");  // A0h0,B0h0 landed
  __builtin_amdgcn_s_barrier();

  for (int t = 0; t < 16; ++t) {
    // ---- P1 (qm0,qn0): stage A(t+1)h0; gate covers p2's A(t)h1 ----
    READ_B(0, t);
    READ_A(0, t);
    if (t < 15) {
      STG_A(t + 1, 0);
      asm volatile("s_waitcnt vmcnt(4)" ::: "memory");
    } else {
      asm volatile("s_waitcnt vmcnt(2)" ::: "memory");
    }
    __builtin_amdgcn_s_barrier();
    asm volatile("s_waitcnt lgkmcnt(0)" ::: "memory");
    MMA(0, 0);
    __builtin_amdgcn_s_barrier();

    // ---- P2 (qm1,qn0): stage B(t+1)h0; gate covers p3's B(t)h1 ----
    READ_A(1, t);
    if (t < 15) {
      STG_B(t + 1, 0);
      asm volatile("s_waitcnt vmcnt(4)" ::: "memory");
    } else {
      asm volatile("s_waitcnt vmcnt(0)" ::: "memory");
    }
    __builtin_amdgcn_s_barrier();
    asm volatile("s_waitcnt lgkmcnt(0)" ::: "memory");
    MMA(1, 0);
    __builtin_amdgcn_s_barrier();

    // ---- P3 (qm0,qn1): stage A(t+1)h1; no gate ----
    READ_B(1, t);
    READ_A(0, t);
    if (t < 15) STG_A(t + 1, 1);
    __builtin_amdgcn_s_barrier();
    asm volatile("s_waitcnt lgkmcnt(0)" ::: "memory");
    MMA(0, 1);
    __builtin_amdgcn_s_barrier();

    // ---- P4 (qm1,qn1): stage B(t+1)h1; gate covers next p1's h0 pair ----
    READ_A(1, t);
    if (t < 15) {
      STG_B(t + 1, 1);
      asm volatile("s_waitcnt vmcnt(4)" ::: "memory");
    }
    __builtin_amdgcn_s_barrier();
    asm volatile("s_waitcnt lgkmcnt(0)" ::: "memory");
    MMA(1, 1);
    __builtin_amdgcn_s_barrier();
  }

  // ---- epilogue: Q/K -> qk (Q scaled); V -> vt transposed ----
#pragma unroll
  for (int mm = 0; mm < 8; mm++)
#pragma unroll
    for (int nn = 0; nn < 4; nn++) {
      int col = bcol + nn * 64 + wc * 16 + frow;
      int row0 = brow + mm * 32 + wr * 16 + fgrp * 4;
      if (col < N_QK) {
        float sc = (col < DMODEL) ? 0.125f : 1.0f;
#pragma unroll
        for (int j = 0; j < 4; j++)
          qk[(size_t)(row0 + j) * N_QK + col] = __float2bfloat16(acc[mm][nn][j] * sc);
      } else {
        ushort4 pack;
        pack.x = __bfloat16_as_ushort(__float2bfloat16(acc[mm][nn][0]));
        pack.y = __bfloat16_as_ushort(__float2bfloat16(acc[mm][nn][1]));
        pack.z = __bfloat16_as_ushort(__float2bfloat16(acc[mm][nn][2]));
        pack.w = __bfloat16_as_ushort(__float2bfloat16(acc[mm][nn][3]));
        *(ushort4*)((unsigned short*)vt + (size_t)(col - N_QK) * T_SEQ + row0) = pack;
      }
    }
#undef STG_A
#undef STG_B
#undef READ_A
#undef READ_B
#undef MMA
}

// ========== output projection: 128x128 tiles, grid 256, 4-slot ring ==========
__global__ __launch_bounds__(256) void gemm_out(
    const __hip_bfloat16* __restrict__ A, const __hip_bfloat16* __restrict__ Bt,
    float* __restrict__ C) {
  const int K = DMODEL, N = DMODEL;
  __shared__ alignas(16) __hip_bfloat16 Ab[4][128 * 32];
  __shared__ alignas(16) __hip_bfloat16 Bb[4][128 * 32];
  const int tid = threadIdx.x, lane = tid & 63, w = tid >> 6;
  const int wr = w >> 1, wc = w & 1;
  const int frow = lane & 15, fgrp = lane >> 4;
  const int bid = blockIdx.x;
  const int sbid = (bid & 7) * 32 + (bid >> 3);
  const int mb = sbid >> 3, nb = sbid & 7;
  const int brow = mb * 128, bcol = nb * 128;

  const int sr = tid >> 2;
  const int swz = ((tid & 3) ^ ((sr >> 1) & 3)) << 3;
  const __hip_bfloat16* aA = A + (size_t)(brow + sr) * K + swz;
  const __hip_bfloat16* aB = Bt + (size_t)(bcol + sr) * K + swz;
  const int dlo = sr * 32 + (tid & 3) * 8;
  const int dhi = (sr + 64) * 32 + (tid & 3) * 8;

  f32x4 acc[4][4] = {};
#pragma unroll
  for (int t = 0; t < 3; t++) {
    gload_lds16(aA + t * 32, &Ab[t][dlo]);
    gload_lds16(aA + 64 * (size_t)K + t * 32, &Ab[t][dhi]);
    gload_lds16(aB + t * 32, &Bb[t][dlo]);
    gload_lds16(aB + 64 * (size_t)K + t * 32, &Bb[t][dhi]);
  }
  for (int t = 0; t < 32; ++t) {
    if (t < 30)
      asm volatile("s_waitcnt vmcnt(8)" ::: "memory");
    else if (t == 30)
      asm volatile("s_waitcnt vmcnt(4)" ::: "memory");
    else
      asm volatile("s_waitcnt vmcnt(0)" ::: "memory");
    __builtin_amdgcn_s_barrier();
    const __hip_bfloat16* As = Ab[t & 3];
    const __hip_bfloat16* Bs = Bb[t & 3];
    if (t + 3 < 32) {
      gload_lds16(aA + (t + 3) * 32, &Ab[(t + 3) & 3][dlo]);
      gload_lds16(aA + 64 * (size_t)K + (t + 3) * 32, &Ab[(t + 3) & 3][dhi]);
      gload_lds16(aB + (t + 3) * 32, &Bb[(t + 3) & 3][dlo]);
      gload_lds16(aB + 64 * (size_t)K + (t + 3) * 32, &Bb[(t + 3) & 3][dhi]);
    }
    bf16x8 af[4], bfr[4];
#pragma unroll
    for (int m = 0; m < 4; m++) {
      int row = wr * 64 + m * 16 + frow;
      af[m] = *(const bf16x8*)(As + row * 32 + ((fgrp ^ ((row >> 1) & 3)) << 3));
    }
#pragma unroll
    for (int n = 0; n < 4; n++) {
      int row = wc * 64 + n * 16 + frow;
      bfr[n] = *(const bf16x8*)(Bs + row * 32 + ((fgrp ^ ((row >> 1) & 3)) << 3));
    }
    __builtin_amdgcn_s_barrier();
    __builtin_amdgcn_s_setprio(1);
#pragma unroll
    for (int m = 0; m < 4; m++)
#pragma unroll
      for (int n = 0; n < 4; n++)
        acc[m][n] = __builtin_amdgcn_mfma_f32_16x16x32_bf16(af[m], bfr[n], acc[m][n], 0, 0, 0);
    __builtin_amdgcn_s_setprio(0);
  }
  const int orow0 = brow + wr * 64 + 4 * fgrp;
  const int ocol0 = bcol + wc * 64 + frow;
#pragma unroll
  for (int m = 0; m < 4; m++)
#pragma unroll
    for (int n = 0; n < 4; n++)
#pragma unroll
      for (int j = 0; j < 4; j++)
        C[(size_t)(orow0 + m * 16 + j) * N + ocol0 + n * 16] = acc[m][n][j];
}

// ------- sliding-window flash attention: V single-buffered, 4 blocks/CU -------
__global__ __launch_bounds__(256) void swa_kernel(
    const __hip_bfloat16* __restrict__ qk, const __hip_bfloat16* __restrict__ vt,
    __hip_bfloat16* __restrict__ attn_out) {
  const int b = blockIdx.x;
  const int s = (b & 7) * 128 + (b >> 3);
  const int h = s >> 6;
  const int qb = s & 63;
  const int tid = threadIdx.x;
  const int lane = tid & 63;
  const int w = tid >> 6;
  const int frow = lane & 15;
  const int fgrp = lane >> 4;
  const int fk = fgrp * 8;

  __shared__ alignas(16) __hip_bfloat16 Ks[2][64 * 64];
  __shared__ alignas(16) __hip_bfloat16 Vs[64 * 64];
  __shared__ alignas(16) __hip_bfloat16 Pl[4][16 * 72];

  const int qrow_g = qb * 64 + w * 16 + frow;
  bf16x8 aq[2];
  {
    const __hip_bfloat16* qptr = qk + (size_t)qrow_g * N_QK + h * DH;
    aq[0] = *(const bf16x8*)(qptr + fk);
    aq[1] = *(const bf16x8*)(qptr + 32 + fk);
  }

  f32x4 o[4] = {};
  float l_run[4] = {0.f, 0.f, 0.f, 0.f};

  const int srow = lane >> 3;
  const int ssw = (((lane & 7) ^ srow) << 3);
  const __hip_bfloat16* kbase =
      qk + (size_t)(w * 16 + srow) * N_QK + DMODEL + h * DH + ssw;
  const __hip_bfloat16* vbase =
      vt + (size_t)(h * DH + w * 16 + srow) * T_SEQ + ssw;

  const int kb0 = qb >= 4 ? qb - 4 : 0;

  {
    const __hip_bfloat16* ks = kbase + (size_t)kb0 * 64 * N_QK;
    gload_lds16(ks, &Ks[0][w * 16 * 64]);
    gload_lds16(ks + 8 * (size_t)N_QK, &Ks[0][(w * 16 + 8) * 64]);
  }

  for (int kb = kb0; kb <= qb; kb++) {
    const int buf = (kb - kb0) & 1;
    {
      const __hip_bfloat16* vs = vbase + kb * 64;
      gload_lds16(vs, &Vs[w * 16 * 64]);
      gload_lds16(vs + 8 * (size_t)T_SEQ, &Vs[(w * 16 + 8) * 64]);
    }
    if (kb < qb) {
      const __hip_bfloat16* ks = kbase + (size_t)(kb + 1) * 64 * N_QK;
      gload_lds16(ks, &Ks[buf ^ 1][w * 16 * 64]);
      gload_lds16(ks + 8 * (size_t)N_QK, &Ks[buf ^ 1][(w * 16 + 8) * 64]);
      asm volatile("s_waitcnt vmcnt(4)" ::: "memory");
    } else {
      asm volatile("s_waitcnt vmcnt(2)" ::: "memory");
    }
    __builtin_amdgcn_s_barrier();

    f32x4 sc[4];
#pragma unroll
    for (int n = 0; n < 4; n++) sc[n] = (f32x4){0.f, 0.f, 0.f, 0.f};
#pragma unroll
    for (int n = 0; n < 4; n++) {
      int rowk = n * 16 + frow;
      int x = rowk & 7;
      bf16x8 bk0 = *(const bf16x8*)(&Ks[buf][rowk * 64 + ((fgrp ^ x) << 3)]);
      bf16x8 bk1 = *(const bf16x8*)(&Ks[buf][rowk * 64 + (((4 + fgrp) ^ x) << 3)]);
      sc[n] = __builtin_amdgcn_mfma_f32_16x16x32_bf16(aq[0], bk0, sc[n], 0, 0, 0);
      sc[n] = __builtin_amdgcn_mfma_f32_16x16x32_bf16(aq[1], bk1, sc[n], 0, 0, 0);
    }

    const bool edge_hi = (kb == qb);
    const bool edge_lo = (kb == qb - 4);
#pragma unroll
    for (int r = 0; r < 4; r++) {
      const int row_l = w * 16 + 4 * fgrp + r;
      float rs = 0.f;
#pragma unroll
      for (int n = 0; n < 4; n++) {
        int col_l = n * 16 + frow;
        bool valid = (!edge_hi || col_l <= row_l) && (!edge_lo || col_l > row_l);
        float p = valid ? __expf(sc[n][r]) : 0.f;
        sc[n][r] = p;
        rs += p;
      }
      l_run[r] += rs;
    }

    __hip_bfloat16* pw = &Pl[w][0];
#pragma unroll
    for (int n = 0; n < 4; n++)
#pragma unroll
      for (int r = 0; r < 4; r++)
        pw[(4 * fgrp + r) * 72 + n * 16 + frow] = __float2bfloat16(sc[n][r]);

    if (kb < qb)
      asm volatile("s_waitcnt vmcnt(2)" ::: "memory");
    else
      asm volatile("s_waitcnt vmcnt(0)" ::: "memory");
    __builtin_amdgcn_s_barrier();

#pragma unroll
    for (int c = 0; c < 2; c++) {
      bf16x8 ap = *(const bf16x8*)(pw + frow * 72 + c * 32 + fk);
#pragma unroll
      for (int nd = 0; nd < 4; nd++) {
        int rowd = nd * 16 + frow;
        int x = rowd & 7;
        bf16x8 bv = *(const bf16x8*)(&Vs[rowd * 64 + (((c * 4 + fgrp) ^ x) << 3)]);
        o[nd] = __builtin_amdgcn_mfma_f32_16x16x32_bf16(ap, bv, o[nd], 0, 0, 0);
      }
    }
    __builtin_amdgcn_s_barrier();
  }

  float linv[4];
#pragma unroll
  for (int r = 0; r < 4; r++) {
    float l = l_run[r];
    l += __shfl_xor(l, 1);
    l += __shfl_xor(l, 2);
    l += __shfl_xor(l, 4);
    l += __shfl_xor(l, 8);
    linv[r] = 1.0f / l;
  }
#pragma unroll
  for (int nd = 0; nd < 4; nd++)
#pragma unroll
    for (int r = 0; r < 4; r++) {
      float v = o[nd][r] * linv[r];
      attn_out[(size_t)(qb * 64 + w * 16 + 4 * fgrp + r) * DMODEL + h * DH + nd * 16 + frow] =
          __float2bfloat16(v);
    }
}

// ---------------- launch ----------------
extern "C" void kernel_launch(void* const* d_in, const int* in_sizes, int n_in,
                              void* d_out, int out_size, void* d_ws, size_t ws_size,
                              hipStream_t stream) {
  const float* x = (const float*)d_in[0];
  const float* w_qkv = (const float*)d_in[1];
  const float* w_out = (const float*)d_in[2];
  float* out = (float*)d_out;

  char* ws = (char*)d_ws;
  __hip_bfloat16* x_bf = (__hip_bfloat16*)ws;                  //  0..8MB
  __hip_bfloat16* wqkvT = (__hip_bfloat16*)(ws + 8388608);     //  8..14MB
  __hip_bfloat16* woutT = (__hip_bfloat16*)(ws + 14680064);    // 14..16MB
  __hip_bfloat16* qk_bf = (__hip_bfloat16*)(ws + 16777216);    // 16..32MB (4096x2048)
  __hip_bfloat16* vt = (__hip_bfloat16*)(ws + 33554432);       // 32..40MB (1024x4096)
  __hip_bfloat16* attn_bf = (__hip_bfloat16*)(ws + 41943040);  // 40..48MB

  prep_kernel<<<8192, 256, 0, stream>>>(x, w_qkv, w_out, x_bf, wqkvT, woutT);

  gemm8_qkv<<<(T_SEQ / 256) * (N_QKV / 256), 512, 0, stream>>>(x_bf, wqkvT, qk_bf, vt);

  swa_kernel<<<(T_SEQ / 64) * NH, 256, 0, stream>>>(qk_bf, vt, attn_bf);

  gemm_out<<<256, 256, 0, stream>>>(attn_bf, woutT, out);
}

// Round 13
// 80.363 us; speedup vs baseline: 1.1569x; 1.1569x over previous
//
#include <hip/hip_runtime.h>
#include <hip/hip_bf16.h>

#define T_SEQ 4096
#define DMODEL 1024
#define NH 16
#define DH 64
#define N_QKV 3072
#define N_QK 2048

typedef __attribute__((ext_vector_type(8))) short bf16x8;
typedef __attribute__((ext_vector_type(4))) float f32x4;

__device__ inline void gload_lds16(const __hip_bfloat16* g, __hip_bfloat16* l) {
  __builtin_amdgcn_global_load_lds(
      (const __attribute__((address_space(1))) void*)g,
      (__attribute__((address_space(3))) void*)l, 16, 0, 0);
}

// ---------------- fused prep: cast x + transpose both weights ----------------
__global__ void prep_kernel(const float* __restrict__ x,
                            const float* __restrict__ w_qkv,
                            const float* __restrict__ w_out,
                            __hip_bfloat16* __restrict__ x_bf,
                            __hip_bfloat16* __restrict__ wqkvT,
                            __hip_bfloat16* __restrict__ woutT) {
  __shared__ float tile[32][33];
  const int b = blockIdx.x;
  if (b < 4096) {
    int i = (b * 256 + threadIdx.x) * 4;
    float4 v = *(const float4*)(x + i);
    ushort4 o;
    o.x = __bfloat16_as_ushort(__float2bfloat16(v.x));
    o.y = __bfloat16_as_ushort(__float2bfloat16(v.y));
    o.z = __bfloat16_as_ushort(__float2bfloat16(v.z));
    o.w = __bfloat16_as_ushort(__float2bfloat16(v.w));
    *(ushort4*)((unsigned short*)x_bf + i) = o;
    return;
  }
  const float* in;
  __hip_bfloat16* out;
  int NN, KK, bn, bk;
  if (b < 7168) {
    int idx = b - 4096;
    in = w_qkv; out = wqkvT; NN = N_QKV; KK = DMODEL;
    bn = (idx % 96) * 32; bk = (idx / 96) * 32;
  } else {
    int idx = b - 7168;
    in = w_out; out = woutT; NN = DMODEL; KK = DMODEL;
    bn = (idx % 32) * 32; bk = (idx / 32) * 32;
  }
  int tx = threadIdx.x & 31, ty = threadIdx.x >> 5;
#pragma unroll
  for (int r = 0; r < 32; r += 8)
    tile[ty + r][tx] = in[(size_t)(bk + ty + r) * NN + bn + tx];
  __syncthreads();
#pragma unroll
  for (int r = 0; r < 32; r += 8)
    out[(size_t)(bn + ty + r) * KK + bk + tx] = __float2bfloat16(tile[tx][ty + r]);
}

// ================= 256x192 4-phase QKV GEMM, grid 256 (R7 structure) ========
__global__ __launch_bounds__(512, 2) void gemm8_qkv(
    const __hip_bfloat16* __restrict__ A, const __hip_bfloat16* __restrict__ Bt,
    __hip_bfloat16* __restrict__ qk, __hip_bfloat16* __restrict__ vt) {
  const int K = DMODEL;
  __shared__ alignas(16) __hip_bfloat16 Ab[3][256 * 64];
  __shared__ alignas(16) __hip_bfloat16 Bb[2][192 * 64];

  const int tid = threadIdx.x;
  const int lane = tid & 63;
  const int w = tid >> 6;
  const int wr = w >> 2, wc = w & 3;
  const int frow = lane & 15, fgrp = lane >> 4;

  const int bid = blockIdx.x;
  const int sbid = (bid & 7) * 32 + (bid >> 3);
  const int mb = sbid >> 4, nb = sbid & 15;
  const int brow = mb << 8, bcol = nb * 192;

  const int srow = lane >> 3;
  const int sslot = (lane & 7) ^ srow;
  const __hip_bfloat16* aSrcA = A + (size_t)(brow + w * 32 + srow) * K + sslot * 8;
  const __hip_bfloat16* aSrcB = Bt + (size_t)(bcol + w * 24 + srow) * K + sslot * 8;
  const int dstA = (w * 32 + srow) * 64 + (lane & 7) * 8;
  const int dstB = (w * 24 + srow) * 64 + (lane & 7) * 8;

  f32x4 acc[8][3] = {};

#pragma unroll
  for (int i = 0; i < 4; i++)
    gload_lds16(aSrcA + (size_t)(i * 8) * K, &Ab[0][dstA + i * 8 * 64]);
#pragma unroll
  for (int i = 0; i < 3; i++)
    gload_lds16(aSrcB + (size_t)(i * 8) * K, &Bb[0][dstB + i * 8 * 64]);
#pragma unroll
  for (int i = 0; i < 4; i++)
    gload_lds16(aSrcA + (size_t)(i * 8) * K + 64, &Ab[1][dstA + i * 8 * 64]);

  for (int t = 0; t < 16; ++t) {
    if (t < 15)
      asm volatile("s_waitcnt vmcnt(4)" ::: "memory");
    else
      asm volatile("s_waitcnt vmcnt(0)" ::: "memory");
    __builtin_amdgcn_s_barrier();

    const __hip_bfloat16* As = &Ab[t % 3][0];
    const __hip_bfloat16* Bs = &Bb[t & 1][0];
    bf16x8 bfrag[3][2], afrag[4][2];

#pragma unroll
    for (int n = 0; n < 3; n++) {
      int row = wc * 48 + n * 16 + frow;
#pragma unroll
      for (int kh = 0; kh < 2; kh++) {
        int slot = (kh * 4 + fgrp) ^ (row & 7);
        bfrag[n][kh] = *(const bf16x8*)(Bs + row * 64 + slot * 8);
      }
    }
#pragma unroll
    for (int m = 0; m < 4; m++) {
      int row = wr * 128 + m * 16 + frow;
#pragma unroll
      for (int kh = 0; kh < 2; kh++) {
        int slot = (kh * 4 + fgrp) ^ (row & 7);
        afrag[m][kh] = *(const bf16x8*)(As + row * 64 + slot * 8);
      }
    }
    if (t + 1 < 16) {
      __hip_bfloat16* bd = &Bb[(t + 1) & 1][0];
#pragma unroll
      for (int i = 0; i < 3; i++)
        gload_lds16(aSrcB + (size_t)(i * 8) * K + (t + 1) * 64, bd + dstB + i * 8 * 64);
    }
    __builtin_amdgcn_s_barrier();
    __builtin_amdgcn_s_setprio(1);
#pragma unroll
    for (int m = 0; m < 4; m++)
#pragma unroll
      for (int n = 0; n < 3; n++) {
        acc[m][n] = __builtin_amdgcn_mfma_f32_16x16x32_bf16(afrag[m][0], bfrag[n][0], acc[m][n], 0, 0, 0);
        acc[m][n] = __builtin_amdgcn_mfma_f32_16x16x32_bf16(afrag[m][1], bfrag[n][1], acc[m][n], 0, 0, 0);
      }
    __builtin_amdgcn_s_setprio(0);
    __builtin_amdgcn_s_barrier();

#pragma unroll
    for (int m = 0; m < 4; m++) {
      int row = wr * 128 + (m + 4) * 16 + frow;
#pragma unroll
      for (int kh = 0; kh < 2; kh++) {
        int slot = (kh * 4 + fgrp) ^ (row & 7);
        afrag[m][kh] = *(const bf16x8*)(As + row * 64 + slot * 8);
      }
    }
    if (t + 2 < 16) {
      __hip_bfloat16* ad = &Ab[(t + 2) % 3][0];
#pragma unroll
      for (int i = 0; i < 4; i++)
        gload_lds16(aSrcA + (size_t)(i * 8) * K + (t + 2) * 64, ad + dstA + i * 8 * 64);
    }
    __builtin_amdgcn_s_barrier();
    __builtin_amdgcn_s_setprio(1);
#pragma unroll
    for (int m = 0; m < 4; m++)
#pragma unroll
      for (int n = 0; n < 3; n++) {
        acc[m + 4][n] = __builtin_amdgcn_mfma_f32_16x16x32_bf16(afrag[m][0], bfrag[n][0], acc[m + 4][n], 0, 0, 0);
        acc[m + 4][n] = __builtin_amdgcn_mfma_f32_16x16x32_bf16(afrag[m][1], bfrag[n][1], acc[m + 4][n], 0, 0, 0);
      }
    __builtin_amdgcn_s_setprio(0);
  }

  const int orow0 = brow + wr * 128 + 4 * fgrp;
  const int ocol0 = bcol + wc * 48 + frow;
#pragma unroll
  for (int m = 0; m < 8; m++)
#pragma unroll
    for (int n = 0; n < 3; n++) {
      int col = ocol0 + n * 16;
      int row0 = orow0 + m * 16;
      if (col < N_QK) {
        float sc = (col < DMODEL) ? 0.125f : 1.0f;
#pragma unroll
        for (int j = 0; j < 4; j++)
          qk[(size_t)(row0 + j) * N_QK + col] = __float2bfloat16(acc[m][n][j] * sc);
      } else {
        ushort4 pack;
        pack.x = __bfloat16_as_ushort(__float2bfloat16(acc[m][n][0]));
        pack.y = __bfloat16_as_ushort(__float2bfloat16(acc[m][n][1]));
        pack.z = __bfloat16_as_ushort(__float2bfloat16(acc[m][n][2]));
        pack.w = __bfloat16_as_ushort(__float2bfloat16(acc[m][n][3]));
        *(ushort4*)((unsigned short*)vt + (size_t)(col - N_QK) * T_SEQ + row0) = pack;
      }
    }
}

// ========== output projection: 128x128 tiles, grid 256, 4-slot ring ==========
__global__ __launch_bounds__(256) void gemm_out(
    const __hip_bfloat16* __restrict__ A, const __hip_bfloat16* __restrict__ Bt,
    float* __restrict__ C) {
  const int K = DMODEL, N = DMODEL;
  __shared__ alignas(16) __hip_bfloat16 Ab[4][128 * 32];
  __shared__ alignas(16) __hip_bfloat16 Bb[4][128 * 32];
  const int tid = threadIdx.x, lane = tid & 63, w = tid >> 6;
  const int wr = w >> 1, wc = w & 1;
  const int frow = lane & 15, fgrp = lane >> 4;
  const int bid = blockIdx.x;
  const int sbid = (bid & 7) * 32 + (bid >> 3);
  const int mb = sbid >> 3, nb = sbid & 7;
  const int brow = mb * 128, bcol = nb * 128;

  const int sr = tid >> 2;
  const int swz = ((tid & 3) ^ ((sr >> 1) & 3)) << 3;
  const __hip_bfloat16* aA = A + (size_t)(brow + sr) * K + swz;
  const __hip_bfloat16* aB = Bt + (size_t)(bcol + sr) * K + swz;
  const int dlo = sr * 32 + (tid & 3) * 8;
  const int dhi = (sr + 64) * 32 + (tid & 3) * 8;

  f32x4 acc[4][4] = {};
#pragma unroll
  for (int t = 0; t < 3; t++) {
    gload_lds16(aA + t * 32, &Ab[t][dlo]);
    gload_lds16(aA + 64 * (size_t)K + t * 32, &Ab[t][dhi]);
    gload_lds16(aB + t * 32, &Bb[t][dlo]);
    gload_lds16(aB + 64 * (size_t)K + t * 32, &Bb[t][dhi]);
  }
  for (int t = 0; t < 32; ++t) {
    if (t < 30)
      asm volatile("s_waitcnt vmcnt(8)" ::: "memory");
    else if (t == 30)
      asm volatile("s_waitcnt vmcnt(4)" ::: "memory");
    else
      asm volatile("s_waitcnt vmcnt(0)" ::: "memory");
    __builtin_amdgcn_s_barrier();
    const __hip_bfloat16* As = Ab[t & 3];
    const __hip_bfloat16* Bs = Bb[t & 3];
    if (t + 3 < 32) {
      gload_lds16(aA + (t + 3) * 32, &Ab[(t + 3) & 3][dlo]);
      gload_lds16(aA + 64 * (size_t)K + (t + 3) * 32, &Ab[(t + 3) & 3][dhi]);
      gload_lds16(aB + (t + 3) * 32, &Bb[(t + 3) & 3][dlo]);
      gload_lds16(aB + 64 * (size_t)K + (t + 3) * 32, &Bb[(t + 3) & 3][dhi]);
    }
    bf16x8 af[4], bfr[4];
#pragma unroll
    for (int m = 0; m < 4; m++) {
      int row = wr * 64 + m * 16 + frow;
      af[m] = *(const bf16x8*)(As + row * 32 + ((fgrp ^ ((row >> 1) & 3)) << 3));
    }
#pragma unroll
    for (int n = 0; n < 4; n++) {
      int row = wc * 64 + n * 16 + frow;
      bfr[n] = *(const bf16x8*)(Bs + row * 32 + ((fgrp ^ ((row >> 1) & 3)) << 3));
    }
    __builtin_amdgcn_s_barrier();
    __builtin_amdgcn_s_setprio(1);
#pragma unroll
    for (int m = 0; m < 4; m++)
#pragma unroll
      for (int n = 0; n < 4; n++)
        acc[m][n] = __builtin_amdgcn_mfma_f32_16x16x32_bf16(af[m], bfr[n], acc[m][n], 0, 0, 0);
    __builtin_amdgcn_s_setprio(0);
  }
  const int orow0 = brow + wr * 64 + 4 * fgrp;
  const int ocol0 = bcol + wc * 64 + frow;
#pragma unroll
  for (int m = 0; m < 4; m++)
#pragma unroll
    for (int n = 0; n < 4; n++)
#pragma unroll
      for (int j = 0; j < 4; j++)
        C[(size_t)(orow0 + m * 16 + j) * N + ocol0 + n * 16] = acc[m][n][j];
}

// ------- sliding-window flash attention: V single-buffered, 4 blocks/CU -------
// Race-fix (R12): PV gate is vmcnt(0) — order-robust regardless of how the
// scheduler interleaves the V(kb)/K(kb+1) load groups. Each iteration's loads
// are fully drained before PV; K(kb+1) still overlaps QK^T+softmax.
__global__ __launch_bounds__(256) void swa_kernel(
    const __hip_bfloat16* __restrict__ qk, const __hip_bfloat16* __restrict__ vt,
    __hip_bfloat16* __restrict__ attn_out) {
  const int b = blockIdx.x;
  const int s = (b & 7) * 128 + (b >> 3);
  const int h = s >> 6;
  const int qb = s & 63;
  const int tid = threadIdx.x;
  const int lane = tid & 63;
  const int w = tid >> 6;
  const int frow = lane & 15;
  const int fgrp = lane >> 4;
  const int fk = fgrp * 8;

  __shared__ alignas(16) __hip_bfloat16 Ks[2][64 * 64];
  __shared__ alignas(16) __hip_bfloat16 Vs[64 * 64];
  __shared__ alignas(16) __hip_bfloat16 Pl[4][16 * 72];

  const int qrow_g = qb * 64 + w * 16 + frow;
  bf16x8 aq[2];
  {
    const __hip_bfloat16* qptr = qk + (size_t)qrow_g * N_QK + h * DH;
    aq[0] = *(const bf16x8*)(qptr + fk);
    aq[1] = *(const bf16x8*)(qptr + 32 + fk);
  }

  f32x4 o[4] = {};
  float l_run[4] = {0.f, 0.f, 0.f, 0.f};

  const int srow = lane >> 3;
  const int ssw = (((lane & 7) ^ srow) << 3);
  const __hip_bfloat16* kbase =
      qk + (size_t)(w * 16 + srow) * N_QK + DMODEL + h * DH + ssw;
  const __hip_bfloat16* vbase =
      vt + (size_t)(h * DH + w * 16 + srow) * T_SEQ + ssw;

  const int kb0 = qb >= 4 ? qb - 4 : 0;

  // prologue: stage K(kb0)
  {
    const __hip_bfloat16* ks = kbase + (size_t)kb0 * 64 * N_QK;
    gload_lds16(ks, &Ks[0][w * 16 * 64]);
    gload_lds16(ks + 8 * (size_t)N_QK, &Ks[0][(w * 16 + 8) * 64]);
  }

  for (int kb = kb0; kb <= qb; kb++) {
    const int buf = (kb - kb0) & 1;
    // issue K(kb+1) prefetch and V(kb) (relative order irrelevant: PV gate drains)
    if (kb < qb) {
      const __hip_bfloat16* ks = kbase + (size_t)(kb + 1) * 64 * N_QK;
      gload_lds16(ks, &Ks[buf ^ 1][w * 16 * 64]);
      gload_lds16(ks + 8 * (size_t)N_QK, &Ks[buf ^ 1][(w * 16 + 8) * 64]);
    }
    {
      const __hip_bfloat16* vs = vbase + kb * 64;
      gload_lds16(vs, &Vs[w * 16 * 64]);
      gload_lds16(vs + 8 * (size_t)T_SEQ, &Vs[(w * 16 + 8) * 64]);
    }
    // K-gate: K(kb) already drained by previous iteration's vmcnt(0);
    // keep this iteration's loads (4 or 2) in flight. Count-robust.
    if (kb < qb)
      asm volatile("s_waitcnt vmcnt(4)" ::: "memory");
    else
      asm volatile("s_waitcnt vmcnt(2)" ::: "memory");
    __builtin_amdgcn_s_barrier();

    // ---- S = Q K^T (swizzled K reads) ----
    f32x4 sc[4];
#pragma unroll
    for (int n = 0; n < 4; n++) sc[n] = (f32x4){0.f, 0.f, 0.f, 0.f};
#pragma unroll
    for (int n = 0; n < 4; n++) {
      int rowk = n * 16 + frow;
      int x = rowk & 7;
      bf16x8 bk0 = *(const bf16x8*)(&Ks[buf][rowk * 64 + ((fgrp ^ x) << 3)]);
      bf16x8 bk1 = *(const bf16x8*)(&Ks[buf][rowk * 64 + (((4 + fgrp) ^ x) << 3)]);
      sc[n] = __builtin_amdgcn_mfma_f32_16x16x32_bf16(aq[0], bk0, sc[n], 0, 0, 0);
      sc[n] = __builtin_amdgcn_mfma_f32_16x16x32_bf16(aq[1], bk1, sc[n], 0, 0, 0);
    }

    // ---- mask + exp + deferred row-sum ----
    const bool edge_hi = (kb == qb);
    const bool edge_lo = (kb == qb - 4);
#pragma unroll
    for (int r = 0; r < 4; r++) {
      const int row_l = w * 16 + 4 * fgrp + r;
      float rs = 0.f;
#pragma unroll
      for (int n = 0; n < 4; n++) {
        int col_l = n * 16 + frow;
        bool valid = (!edge_hi || col_l <= row_l) && (!edge_lo || col_l > row_l);
        float p = valid ? __expf(sc[n][r]) : 0.f;
        sc[n][r] = p;
        rs += p;
      }
      l_run[r] += rs;
    }

    // ---- P -> per-wave LDS ----
    __hip_bfloat16* pw = &Pl[w][0];
#pragma unroll
    for (int n = 0; n < 4; n++)
#pragma unroll
      for (int r = 0; r < 4; r++)
        pw[(4 * fgrp + r) * 72 + n * 16 + frow] = __float2bfloat16(sc[n][r]);

    // ---- PV gate: drain ALL outstanding loads (order-robust) ----
    asm volatile("s_waitcnt vmcnt(0)" ::: "memory");
    __builtin_amdgcn_s_barrier();

#pragma unroll
    for (int c = 0; c < 2; c++) {
      bf16x8 ap = *(const bf16x8*)(pw + frow * 72 + c * 32 + fk);
#pragma unroll
      for (int nd = 0; nd < 4; nd++) {
        int rowd = nd * 16 + frow;
        int x = rowd & 7;
        bf16x8 bv = *(const bf16x8*)(&Vs[rowd * 64 + (((c * 4 + fgrp) ^ x) << 3)]);
        o[nd] = __builtin_amdgcn_mfma_f32_16x16x32_bf16(ap, bv, o[nd], 0, 0, 0);
      }
    }
    __builtin_amdgcn_s_barrier();  // protect Ks[buf^1]/Vs for next iteration
  }

  // ---- epilogue ----
  float linv[4];
#pragma unroll
  for (int r = 0; r < 4; r++) {
    float l = l_run[r];
    l += __shfl_xor(l, 1);
    l += __shfl_xor(l, 2);
    l += __shfl_xor(l, 4);
    l += __shfl_xor(l, 8);
    linv[r] = 1.0f / l;
  }
#pragma unroll
  for (int nd = 0; nd < 4; nd++)
#pragma unroll
    for (int r = 0; r < 4; r++) {
      float v = o[nd][r] * linv[r];
      attn_out[(size_t)(qb * 64 + w * 16 + 4 * fgrp + r) * DMODEL + h * DH + nd * 16 + frow] =
          __float2bfloat16(v);
    }
}

// ---------------- launch ----------------
extern "C" void kernel_launch(void* const* d_in, const int* in_sizes, int n_in,
                              void* d_out, int out_size, void* d_ws, size_t ws_size,
                              hipStream_t stream) {
  const float* x = (const float*)d_in[0];
  const float* w_qkv = (const float*)d_in[1];
  const float* w_out = (const float*)d_in[2];
  float* out = (float*)d_out;

  char* ws = (char*)d_ws;
  __hip_bfloat16* x_bf = (__hip_bfloat16*)ws;                  //  0..8MB
  __hip_bfloat16* wqkvT = (__hip_bfloat16*)(ws + 8388608);     //  8..14MB
  __hip_bfloat16* woutT = (__hip_bfloat16*)(ws + 14680064);    // 14..16MB
  __hip_bfloat16* qk_bf = (__hip_bfloat16*)(ws + 16777216);    // 16..32MB (4096x2048)
  __hip_bfloat16* vt = (__hip_bfloat16*)(ws + 33554432);       // 32..40MB (1024x4096)
  __hip_bfloat16* attn_bf = (__hip_bfloat16*)(ws + 41943040);  // 40..48MB

  prep_kernel<<<8192, 256, 0, stream>>>(x, w_qkv, w_out, x_bf, wqkvT, woutT);

  gemm8_qkv<<<(T_SEQ / 256) * (N_QKV / 192), 512, 0, stream>>>(x_bf, wqkvT, qk_bf, vt);

  swa_kernel<<<(T_SEQ / 64) * NH, 256, 0, stream>>>(qk_bf, vt, attn_bf);

  gemm_out<<<256, 256, 0, stream>>>(attn_bf, woutT, out);
}